// Round 4
// baseline (251.484 us; speedup 1.0000x reference)
//
#include <hip/hip_runtime.h>
#include <stdint.h>

typedef float f32x4 __attribute__((ext_vector_type(4)));
typedef __bf16 bf16x8 __attribute__((ext_vector_type(8)));
typedef unsigned short ushortx8 __attribute__((ext_vector_type(8)));

#define D_DIM 512
#define KGC 10
#define NCLU 8
#define BATCH 32
#define WPOS 250
#define WPAD 256
#define KDIM 3584   // 512*7
#define MROWS 522   // 512 feat + 10 assign
#define MPAD 528    // Y rows per batch
#define MBIG 640    // padded W rows (4 x 160)
#define BM 160      // block m-tile (4 m-slices)
#define BN 128      // block n-tile
#define KSPLIT 2
#define KCHUNK 1792 // KDIM / KSPLIT
#define NS 28       // KCHUNK / 64
#define NT 64       // n-tiles of 128 (N = 8192)

#define ASM_VMCNT16() asm volatile("s_waitcnt vmcnt(16)" ::: "memory")
#define ASM_VMCNT0()  asm volatile("s_waitcnt vmcnt(0)" ::: "memory")
#define ASM_LGKM0()   asm volatile("s_waitcnt lgkmcnt(0)" ::: "memory")
#define BAR() do { __builtin_amdgcn_s_barrier(); __builtin_amdgcn_sched_barrier(0); } while (0)

__device__ __forceinline__ float bf2f(unsigned short u) {
  union { unsigned int i; float f; } v; v.i = ((unsigned int)u) << 16; return v.f;
}
__device__ __forceinline__ unsigned short f2bf(float f) {
  union { float f; unsigned int i; } v; v.f = f;
  unsigned int r = v.i + 0x7FFFu + ((v.i >> 16) & 1u);
  return (unsigned short)(r >> 16);
}

__device__ __forceinline__ void load_lds16(const void* g, void* l) {
  __builtin_amdgcn_global_load_lds(
      (const __attribute__((address_space(1))) void*)g,
      (__attribute__((address_space(3))) void*)l, 16, 0, 0);
}

// ---------------- prep: Wcat(bf16) rows 0..639 = [feat_w ; assign_w ; zeros], bcat fp32 ----------------
__global__ void prep_kernel(const float* __restrict__ fw,
                            const float* __restrict__ fb,
                            const float* __restrict__ aw,
                            const float* __restrict__ ab,
                            unsigned short* __restrict__ Wcat,
                            float* __restrict__ bcat) {
  int r = blockIdx.x;
  unsigned short* dst = Wcat + (size_t)r * KDIM;
  const float* src = (r < D_DIM) ? (fw + (size_t)r * KDIM)
                   : (r < MROWS) ? (aw + (size_t)(r - D_DIM) * KDIM)
                                 : nullptr;
  for (int i = threadIdx.x; i < KDIM / 4; i += 256) {
    unsigned short o0 = 0, o1 = 0, o2 = 0, o3 = 0;
    if (src) {
      float4 v = ((const float4*)src)[i];
      o0 = f2bf(v.x); o1 = f2bf(v.y); o2 = f2bf(v.z); o3 = f2bf(v.w);
    }
    ushort4 o; o.x = o0; o.y = o1; o.z = o2; o.w = o3;
    ((ushort4*)dst)[i] = o;
  }
  if (threadIdx.x == 0)
    bcat[r] = r < D_DIM ? fb[r] : (r < MROWS ? ab[r - D_DIM] : 0.f);
}

// ---------------- fused GEMM: partial C[160m x 128n] over a K-half ------------------------------
// 512 thr (8 waves 2m x 4n, wave 80x32, acc=40 AGPR -> 4 waves/SIMD -> 2 blocks/CU CO-RESIDENT).
// Double-buffered, counted-vmcnt schedule (T4): raw s_barrier, vmcnt(16) not vmcnt(0) in
// steady state -- the 16 prefetched x-loads stay in flight across the barrier.
__global__ __launch_bounds__(512, 4) void gemm_fused(
    const float* __restrict__ x, const unsigned short* __restrict__ Wcat,
    float* __restrict__ P) {
  __shared__ __align__(16) unsigned short Wl[2][BM * 64];  // 2 x 20,480 B swizzled
  __shared__ __align__(16) unsigned short Xl[2][BN * 64];  // 2 x 16,384 B swizzled
  const int tid = threadIdx.x;
  const int nt = blockIdx.x, mh = blockIdx.y, sp = blockIdx.z;
  // dispatch-order note: ids = nt + 64*mh + 256*sp; the 4 mh-sharers of an x-tile
  // differ by 64 -> same XCD (64%8==0); sp=0 blocks (ids 0..255) co-start as round 1.
  const int lane = tid & 63, wv = tid >> 6;     // 8 waves
  const int wm = wv >> 2, wn = wv & 3;          // 2m x 4n -> wave 80x32
  const int fr = lane & 15, kg = lane >> 4;
  const int sx = fr & 7;
  const int nloc = tid & 127, oc = tid >> 7;    // staging: col nloc, octets oc & oc+4
  const int nglob = nt * BN + nloc;
  const int b = nglob >> 8, ncol = nglob & 255;
  const bool okn = ncol < WPOS;
  const float* xb = x + (size_t)b * KDIM * WPOS + ncol;
  const int kbase = sp * KCHUNK;
  const unsigned short* Wg = Wcat + (size_t)mh * BM * KDIM + kbase;

  float xr[16];
  auto loadx = [&](int st) {
#pragma unroll
    for (int pass = 0; pass < 2; pass++) {
      int k0 = kbase + st * 64 + (oc + 4 * pass) * 8;
#pragma unroll
      for (int e = 0; e < 8; e++)
        xr[pass * 8 + e] = okn ? xb[(size_t)(k0 + e) * WPOS] : 0.f;
    }
  };
  // W lds-dma: 160 rows x 8 octets = 1280 slots. it=0,1: slots tid, 512+tid.
  // it=2: slots 1024 + (tid&255) -- waves 4..7 duplicate waves 0..3's range with
  // identical data (benign) so EVERY wave issues exactly 3 dma -> uniform vmcnt.
  auto stageW = [&](int st, int buf) {
#pragma unroll
    for (int it = 0; it < 3; it++) {
      int s = (it < 2) ? it * 512 + tid : 1024 + (tid & 255);
      int row = s >> 3, p = s & 7;
      int blk = p ^ (row & 7);
      load_lds16(Wg + (size_t)row * KDIM + st * 64 + blk * 8, &Wl[buf][s * 8]);
    }
  };
  auto writeX = [&](int buf) {
#pragma unroll
    for (int pass = 0; pass < 2; pass++) {
      int oct = oc + 4 * pass;
      ushortx8 pk;
#pragma unroll
      for (int e = 0; e < 8; e++) pk[e] = f2bf(xr[pass * 8 + e]);
      *(ushortx8*)&Xl[buf][nloc * 64 + (oct ^ (nloc & 7)) * 8] = pk;
    }
  };

  f32x4 acc[5][2];
  const f32x4 zero = {0.f, 0.f, 0.f, 0.f};
#pragma unroll
  for (int f = 0; f < 5; f++) { acc[f][0] = zero; acc[f][1] = zero; }

  // prologue: x(0) -> xr -> Xl[0]; W(0) dma -> Wl[0]; prefetch x(1)
  loadx(0);           // 16 vm
  stageW(0, 0);       // 3 vm (out: 19)
  writeX(0);          // compiler auto-waits vmcnt(3) for xr
  loadx(1);           // 16 vm (out: 3 dma + 16 x)
  ASM_VMCNT16();      // dma(0) landed; x(1) stays in flight
  ASM_LGKM0();
  BAR();

  for (int t = 0; t < NS; ++t) {
    const int cur = t & 1, nxt = cur ^ 1;
    const bool more = (t + 1 < NS);
    if (more) {
      stageW(t + 1, nxt);   // 3 vm  (out: 16 x(t+1) + 3 dma)
      writeX(nxt);          // auto vmcnt(3): x(t+1) landed, dma(t+1) in flight
    }
    if (t + 2 < NS) loadx(t + 2);  // 16 vm (out: 3 dma + 16 x)
#pragma unroll
    for (int ks = 0; ks < 2; ks++) {
      const int off = ((ks * 4 + kg) ^ sx) * 8;
      bf16x8 b0 = *(const bf16x8*)&Xl[cur][(wn * 32 + fr) * 64 + off];
      bf16x8 b1 = *(const bf16x8*)&Xl[cur][(wn * 32 + 16 + fr) * 64 + off];
#pragma unroll
      for (int f = 0; f < 5; f++) {
        bf16x8 af = *(const bf16x8*)&Wl[cur][(wm * 80 + f * 16 + fr) * 64 + off];
        acc[f][0] = __builtin_amdgcn_mfma_f32_16x16x32_bf16(af, b0, acc[f][0], 0, 0, 0);
        acc[f][1] = __builtin_amdgcn_mfma_f32_16x16x32_bf16(af, b1, acc[f][1], 0, 0, 0);
      }
    }
    if (more) {
      if (t + 2 < NS) { ASM_VMCNT16(); }  // drain dma(t+1) only; x(t+2) in flight
      else            { ASM_VMCNT0();  }  // tail: nothing younger than the dma
      ASM_LGKM0();
      BAR();
    }
  }

  // store partials. C/D: col = lane&15 (n), row = kg*4 + r (m within frag)
  float* Pb = P + (size_t)((sp * 4 + mh) * NT + nt) * (BM * BN);
#pragma unroll
  for (int f = 0; f < 5; f++) {
    const int m = wm * 80 + f * 16 + kg * 4;
#pragma unroll
    for (int nf = 0; nf < 2; nf++) {
      const int n = wn * 32 + nf * 16 + fr;
#pragma unroll
      for (int r = 0; r < 4; r++)
        Pb[(size_t)(m + r) * BN + n] = acc[f][nf][r];
    }
  }
}

// ---------------- reduce: Y[b][m][n](bf16) = relu_if_feat( sum_sp P + bias ) ----------------
// block = 16 m-rows x 16 n-octets (full 128 cols); grid (64 nt, 40 m-groups)
__global__ __launch_bounds__(256) void reduce_kernel(
    const float* __restrict__ P, const float* __restrict__ bcat,
    unsigned short* __restrict__ Y) {
  const int nt = blockIdx.x, mg = blockIdx.y;
  const int t = threadIdx.x;
  const int m = mg * 16 + (t >> 4);          // 0..639
  const int nl = (t & 15) * 8;               // n-octet within 128
  if (m >= MPAD) return;
  const int mh = (m >= 480) ? 3 : (m >= 320) ? 2 : (m >= 160) ? 1 : 0;
  const int ml = m - mh * BM;
  const size_t slice = (size_t)BM * BN;
  const size_t base = (size_t)ml * BN + nl;
  float s[8];
#pragma unroll
  for (int e = 0; e < 8; e++) s[e] = 0.f;
#pragma unroll
  for (int sp = 0; sp < KSPLIT; sp++) {
    const float* p = P + ((size_t)((sp * 4 + mh) * NT) + nt) * slice + base;
    float4 a = *(const float4*)p;
    float4 c = *(const float4*)(p + 4);
    s[0] += a.x; s[1] += a.y; s[2] += a.z; s[3] += a.w;
    s[4] += c.x; s[5] += c.y; s[6] += c.z; s[7] += c.w;
  }
  float bias = bcat[m];
  ushortx8 o;
#pragma unroll
  for (int e = 0; e < 8; e++) {
    float v = s[e] + bias;
    if (m < D_DIM) v = fmaxf(v, 0.f);
    o[e] = f2bf(v);
  }
  const int nglob = nt * BN + nl;
  const int bb = nglob >> 8, col = nglob & 255;
  *(ushortx8*)&Y[(size_t)bb * MPAD * WPAD + (size_t)m * WPAD + col] = o;
}

// ---------------- epilogue: softmax, agg, subtract centroids*s_sum, L2-normalize ----------------
// 512 thr (8 waves, 1 d-row per thread), float4 broadcast soft reads,
// 8 independent accumulators to break the fma dependency chain.
__global__ __launch_bounds__(512) void epi_kernel(
    const unsigned short* __restrict__ Y, const float* __restrict__ cent,
    float* __restrict__ out) {
  __shared__ float soft[WPAD];
  __shared__ float red[8];
  const int b = blockIdx.x >> 3, k = blockIdx.x & 7;
  const int tid = threadIdx.x;
  const unsigned short* Yb = Y + (size_t)b * MPAD * WPAD;

  float sv = 0.f;
  if (tid < WPOS) {
    float lg[KGC];
    float mx = -1e30f;
#pragma unroll
    for (int j = 0; j < KGC; j++) {
      lg[j] = bf2f(Yb[(size_t)(D_DIM + j) * WPAD + tid]);
      mx = fmaxf(mx, lg[j]);
    }
    float s = 0.f, ek = 0.f;
#pragma unroll
    for (int j = 0; j < KGC; j++) {
      float e = __expf(lg[j] - mx);
      s += e;
      if (j == k) ek = e;
    }
    sv = ek / s;
  }
  if (tid < WPAD) soft[tid] = sv;   // tids 250..255 write 0
  __syncthreads();

  float v = sv;
#pragma unroll
  for (int o = 32; o > 0; o >>= 1) v += __shfl_down(v, o, 64);
  if ((tid & 63) == 0) red[tid >> 6] = v;
  __syncthreads();
  float ssum = 0.f;
#pragma unroll
  for (int i = 0; i < 8; i++) ssum += red[i];

  float a[8];
#pragma unroll
  for (int u = 0; u < 8; u++) a[u] = 0.f;
  const unsigned short* row = Yb + (size_t)tid * WPAD;
  for (int w = 0; w < WPAD; w += 8) {
    ushortx8 f0 = *(const ushortx8*)(row + w);
    float4 s0 = *(const float4*)&soft[w];
    float4 s1 = *(const float4*)&soft[w + 4];
    a[0] += bf2f(f0[0]) * s0.x;
    a[1] += bf2f(f0[1]) * s0.y;
    a[2] += bf2f(f0[2]) * s0.z;
    a[3] += bf2f(f0[3]) * s0.w;
    a[4] += bf2f(f0[4]) * s1.x;
    a[5] += bf2f(f0[5]) * s1.y;
    a[6] += bf2f(f0[6]) * s1.z;
    a[7] += bf2f(f0[7]) * s1.w;
  }
  float asum = ((a[0] + a[1]) + (a[2] + a[3])) + ((a[4] + a[5]) + (a[6] + a[7]));
  float c = asum - cent[(size_t)tid * KGC + k] * ssum;

  __syncthreads();
  float q = c * c;
#pragma unroll
  for (int o = 32; o > 0; o >>= 1) q += __shfl_down(q, o, 64);
  if ((tid & 63) == 0) red[tid >> 6] = q;
  __syncthreads();
  float nsum = 0.f;
#pragma unroll
  for (int i = 0; i < 8; i++) nsum += red[i];
  float norm = sqrtf(nsum);
  float inv = 1.f / fmaxf(norm, 1e-12f);

  float* ob = out + (size_t)b * (NCLU * D_DIM) + (size_t)k * D_DIM;
  ob[tid] = c * inv;
}

extern "C" void kernel_launch(void* const* d_in, const int* in_sizes, int n_in,
                              void* d_out, int out_size, void* d_ws, size_t ws_size,
                              hipStream_t stream) {
  const float* x  = (const float*)d_in[0];
  const float* fw = (const float*)d_in[1];
  const float* fb = (const float*)d_in[2];
  const float* aw = (const float*)d_in[3];
  const float* ab = (const float*)d_in[4];
  const float* ce = (const float*)d_in[5];
  float* out = (float*)d_out;
  char* ws = (char*)d_ws;

  const size_t WC_BYTES = (size_t)MBIG * KDIM * 2;                      //  4,587,520
  const size_t BC_BYTES = 4096;
  const size_t P_BYTES  = (size_t)KSPLIT * 4 * NT * BM * BN * 4;        // 41,943,040
  unsigned short* Wc = (unsigned short*)(ws);
  float*          bc = (float*)(ws + WC_BYTES);
  float*          P  = (float*)(ws + WC_BYTES + BC_BYTES);
  unsigned short* Yv = (unsigned short*)(ws + WC_BYTES + BC_BYTES + P_BYTES);
  // total ws use ~55.2 MB

  prep_kernel<<<MBIG, 256, 0, stream>>>(fw, fb, aw, ab, Wc, bc);
  gemm_fused<<<dim3(NT, 4, KSPLIT), 512, 0, stream>>>(x, Wc, P);
  reduce_kernel<<<dim3(NT, 40), 256, 0, stream>>>(P, bc, Yv);
  epi_kernel<<<BATCH * NCLU, 512, 0, stream>>>(Yv, ce, out);
}

// Round 5
// 250.833 us; speedup vs baseline: 1.0026x; 1.0026x over previous
//
#include <hip/hip_runtime.h>
#include <stdint.h>

typedef float f32x4 __attribute__((ext_vector_type(4)));
typedef __bf16 bf16x8 __attribute__((ext_vector_type(8)));
typedef unsigned short ushortx8 __attribute__((ext_vector_type(8)));

#define D_DIM 512
#define KGC 10
#define NCLU 8
#define BATCH 32
#define WPOS 250
#define WPAD 256
#define KDIM 3584   // 512*7
#define MROWS 522   // 512 feat + 10 assign
#define MPAD 528    // Y rows per batch
#define MBIG 640    // padded W rows (4 x 160)
#define BM 160      // block m-tile (4 m-slices)
#define BN 128      // block n-tile
#define KSPLIT 2
#define KCHUNK 1792 // KDIM / KSPLIT
#define NS 28       // KCHUNK / 64
#define NT 64       // n-tiles of 128 (N = 8192)
#define KSG 56      // total k-steps (KDIM/64)
// XS: bf16 X pre-arranged in MFMA B-fragment lane order.
// tile (nt, ksg) = 1024 lines x 16B; line L = ks*512 + nf*64 + lane holds
// X[n = nt*128 + nf*16 + (lane&15)][k = ksg*64 + ks*32 + (lane>>4)*8 + e], e=0..7
#define XTILE 8192  // ushorts per (nt,ksg) tile

__device__ __forceinline__ float bf2f(unsigned short u) {
  union { unsigned int i; float f; } v; v.i = ((unsigned int)u) << 16; return v.f;
}
__device__ __forceinline__ unsigned short f2bf(float f) {
  union { float f; unsigned int i; } v; v.f = f;
  unsigned int r = v.i + 0x7FFFu + ((v.i >> 16) & 1u);
  return (unsigned short)(r >> 16);
}

__device__ __forceinline__ void load_lds16(const void* g, void* l) {
  __builtin_amdgcn_global_load_lds(
      (const __attribute__((address_space(1))) void*)g,
      (__attribute__((address_space(3))) void*)l, 16, 0, 0);
}

// ---------------- prep2: W-rows (bf16 concat) + bias + X fragment-order converter ----------------
// blocks 0..639: Wcat row r; blocks 640..4223: XS tile (nt, ksg)
__global__ __launch_bounds__(256) void prep2_kernel(
    const float* __restrict__ fw, const float* __restrict__ fb,
    const float* __restrict__ aw, const float* __restrict__ ab,
    const float* __restrict__ x,
    unsigned short* __restrict__ Wcat, float* __restrict__ bcat,
    unsigned short* __restrict__ XS) {
  const int bid = blockIdx.x;
  const int tid = threadIdx.x;
  if (bid < MBIG) {
    int r = bid;
    unsigned short* dst = Wcat + (size_t)r * KDIM;
    const float* src = (r < D_DIM) ? (fw + (size_t)r * KDIM)
                     : (r < MROWS) ? (aw + (size_t)(r - D_DIM) * KDIM)
                                   : nullptr;
    for (int i = tid; i < KDIM / 4; i += 256) {
      unsigned short o0 = 0, o1 = 0, o2 = 0, o3 = 0;
      if (src) {
        float4 v = ((const float4*)src)[i];
        o0 = f2bf(v.x); o1 = f2bf(v.y); o2 = f2bf(v.z); o3 = f2bf(v.w);
      }
      ushort4 o; o.x = o0; o.y = o1; o.z = o2; o.w = o3;
      ((ushort4*)dst)[i] = o;
    }
    if (tid == 0)
      bcat[r] = r < D_DIM ? fb[r] : (r < MROWS ? ab[r - D_DIM] : 0.f);
  } else {
    const int xt = bid - MBIG;
    const int nt = xt / KSG, ksg = xt - nt * KSG;
    unsigned short* tb = XS + (size_t)(nt * KSG + ksg) * XTILE;
#pragma unroll
    for (int i = 0; i < 4; i++) {
      const int L = tid + 256 * i;
      const int ks = L >> 9, nf = (L >> 6) & 7, lane = L & 63;
      const int fr = lane & 15, kg = lane >> 4;
      const int n = nt * 128 + nf * 16 + fr;
      const int b = n >> 8, col = n & 255;
      const int k0 = ksg * 64 + ks * 32 + kg * 8;
      const float* xp = x + ((size_t)b * KDIM + k0) * WPOS + col;
      ushortx8 pk;
      if (col < WPOS) {
#pragma unroll
        for (int e = 0; e < 8; e++) pk[e] = f2bf(xp[(size_t)e * WPOS]);
      } else {
#pragma unroll
        for (int e = 0; e < 8; e++) pk[e] = 0;
      }
      *(ushortx8*)&tb[(size_t)L * 8] = pk;
    }
  }
}

// ---------------- fused GEMM: partial C[160m x 128n] over a K-half ------------------------------
// 512 thr (8 waves 2m x 4n, wave 80x32). No X staging: B-fragments loaded DIRECTLY
// from XS (fragment-order global) into VGPRs. LDS holds only W (double-buffered,
// swizzled lds-dma). One __syncthreads per K-step; prefetch issued before compute,
// so the barrier's vmcnt(0) drain lands after ~a full compute phase. ~100 regs/wave
// -> 4 waves/SIMD -> TRUE 2 blocks/CU co-residency.
__global__ __launch_bounds__(512, 4) void gemm_fused(
    const unsigned short* __restrict__ XS, const unsigned short* __restrict__ Wcat,
    float* __restrict__ P) {
  __shared__ __align__(16) unsigned short Wl[2][BM * 64];  // 2 x 20,480 B swizzled
  const int tid = threadIdx.x;
  const int nt = blockIdx.x, mh = blockIdx.y, sp = blockIdx.z;
  // ids = nt + 64*mh + 256*sp: the 4 mh-sharers of an XS slice differ by 64 -> same XCD.
  const int lane = tid & 63, wv = tid >> 6;     // 8 waves
  const int wm = wv >> 2, wn = wv & 3;          // 2m x 4n -> wave 80x32
  const int fr = lane & 15, kg = lane >> 4;
  const int sx = fr & 7;
  const unsigned short* Wg = Wcat + (size_t)mh * BM * KDIM + sp * KCHUNK;
  const unsigned short* xsb = XS + (size_t)nt * (KSG * XTILE)
                                 + (size_t)sp * NS * XTILE
                                 + (wn * 1024 + lane * 8);

  // W lds-dma: 160 rows x 8 octets = 1280 slots (2.5/thread).
  // LDS dest linear per-lane; global source pre-swizzled (both-sides rule).
  auto stageW = [&](int st, int buf) {
#pragma unroll
    for (int it = 0; it < 3; it++) {
      int s = it * 512 + tid;
      if (s < BM * 8) {
        int row = s >> 3, p = s & 7;
        int blk = p ^ (row & 7);
        load_lds16(Wg + (size_t)row * KDIM + st * 64 + blk * 8, &Wl[buf][s * 8]);
      }
    }
  };
  auto loadX = [&](int st, bf16x8& x0, bf16x8& x1, bf16x8& x2, bf16x8& x3) {
    const unsigned short* p = xsb + (size_t)st * XTILE;
    x0 = *(const bf16x8*)(p);               // ks0, nf0
    x1 = *(const bf16x8*)(p + 512);         // ks0, nf1
    x2 = *(const bf16x8*)(p + 4096);        // ks1, nf0
    x3 = *(const bf16x8*)(p + 4096 + 512);  // ks1, nf1
  };

  f32x4 acc[5][2];
  const f32x4 zero = {0.f, 0.f, 0.f, 0.f};
#pragma unroll
  for (int f = 0; f < 5; f++) { acc[f][0] = zero; acc[f][1] = zero; }

  auto compute = [&](const unsigned short* wb, bf16x8 xa, bf16x8 xb,
                     bf16x8 xc, bf16x8 xd) {
#pragma unroll
    for (int ks = 0; ks < 2; ks++) {
      bf16x8 b0 = ks ? xc : xa;
      bf16x8 b1 = ks ? xd : xb;
      const int off = ((ks * 4 + kg) ^ sx) * 8;
#pragma unroll
      for (int f = 0; f < 5; f++) {
        bf16x8 af = *(const bf16x8*)&wb[(wm * 80 + f * 16 + fr) * 64 + off];
        acc[f][0] = __builtin_amdgcn_mfma_f32_16x16x32_bf16(af, b0, acc[f][0], 0, 0, 0);
        acc[f][1] = __builtin_amdgcn_mfma_f32_16x16x32_bf16(af, b1, acc[f][1], 0, 0, 0);
      }
    }
  };

  bf16x8 xA0, xA1, xA2, xA3, xB0, xB1, xB2, xB3;

  // prologue: step 0 -> Wl[0] + regs A
  stageW(0, 0);
  loadX(0, xA0, xA1, xA2, xA3);
  __syncthreads();   // vmcnt(0) drain: dma + reg-loads landed

  for (int t = 0; t < NS; t += 2) {
    // even sub-iter: consume Wl[0]/A, prefetch step t+1 -> Wl[1]/B (t+1 <= 27 always)
    stageW(t + 1, 1);
    loadX(t + 1, xB0, xB1, xB2, xB3);
    compute(Wl[0], xA0, xA1, xA2, xA3);
    __syncthreads();
    // odd sub-iter: consume Wl[1]/B, prefetch step t+2 -> Wl[0]/A
    if (t + 2 < NS) {
      stageW(t + 2, 0);
      loadX(t + 2, xA0, xA1, xA2, xA3);
    }
    compute(Wl[1], xB0, xB1, xB2, xB3);
    __syncthreads();
  }

  // store partials. C/D: col = lane&15 (n), row = kg*4 + r (m within frag)
  float* Pb = P + (size_t)((sp * 4 + mh) * NT + nt) * (BM * BN);
#pragma unroll
  for (int f = 0; f < 5; f++) {
    const int m = wm * 80 + f * 16 + kg * 4;
#pragma unroll
    for (int nf = 0; nf < 2; nf++) {
      const int n = wn * 32 + nf * 16 + fr;
#pragma unroll
      for (int r = 0; r < 4; r++)
        Pb[(size_t)(m + r) * BN + n] = acc[f][nf][r];
    }
  }
}

// ---------------- reduce: Y[b][m][n](bf16) = relu_if_feat( sum_sp P + bias ) ----------------
// block = 16 m-rows x 16 n-octets (full 128 cols); grid (64 nt, 40 m-groups)
__global__ __launch_bounds__(256) void reduce_kernel(
    const float* __restrict__ P, const float* __restrict__ bcat,
    unsigned short* __restrict__ Y) {
  const int nt = blockIdx.x, mg = blockIdx.y;
  const int t = threadIdx.x;
  const int m = mg * 16 + (t >> 4);          // 0..639
  const int nl = (t & 15) * 8;               // n-octet within 128
  if (m >= MPAD) return;
  const int mh = (m >= 480) ? 3 : (m >= 320) ? 2 : (m >= 160) ? 1 : 0;
  const int ml = m - mh * BM;
  const size_t slice = (size_t)BM * BN;
  const size_t base = (size_t)ml * BN + nl;
  float s[8];
#pragma unroll
  for (int e = 0; e < 8; e++) s[e] = 0.f;
#pragma unroll
  for (int sp = 0; sp < KSPLIT; sp++) {
    const float* p = P + ((size_t)((sp * 4 + mh) * NT) + nt) * slice + base;
    float4 a = *(const float4*)p;
    float4 c = *(const float4*)(p + 4);
    s[0] += a.x; s[1] += a.y; s[2] += a.z; s[3] += a.w;
    s[4] += c.x; s[5] += c.y; s[6] += c.z; s[7] += c.w;
  }
  float bias = bcat[m];
  ushortx8 o;
#pragma unroll
  for (int e = 0; e < 8; e++) {
    float v = s[e] + bias;
    if (m < D_DIM) v = fmaxf(v, 0.f);
    o[e] = f2bf(v);
  }
  const int nglob = nt * BN + nl;
  const int bb = nglob >> 8, col = nglob & 255;
  *(ushortx8*)&Y[(size_t)bb * MPAD * WPAD + (size_t)m * WPAD + col] = o;
}

// ---------------- epilogue: softmax, agg, subtract centroids*s_sum, L2-normalize ----------------
__global__ __launch_bounds__(512) void epi_kernel(
    const unsigned short* __restrict__ Y, const float* __restrict__ cent,
    float* __restrict__ out) {
  __shared__ float soft[WPAD];
  __shared__ float red[8];
  const int b = blockIdx.x >> 3, k = blockIdx.x & 7;
  const int tid = threadIdx.x;
  const unsigned short* Yb = Y + (size_t)b * MPAD * WPAD;

  float sv = 0.f;
  if (tid < WPOS) {
    float lg[KGC];
    float mx = -1e30f;
#pragma unroll
    for (int j = 0; j < KGC; j++) {
      lg[j] = bf2f(Yb[(size_t)(D_DIM + j) * WPAD + tid]);
      mx = fmaxf(mx, lg[j]);
    }
    float s = 0.f, ek = 0.f;
#pragma unroll
    for (int j = 0; j < KGC; j++) {
      float e = __expf(lg[j] - mx);
      s += e;
      if (j == k) ek = e;
    }
    sv = ek / s;
  }
  if (tid < WPAD) soft[tid] = sv;   // tids 250..255 write 0
  __syncthreads();

  float v = sv;
#pragma unroll
  for (int o = 32; o > 0; o >>= 1) v += __shfl_down(v, o, 64);
  if ((tid & 63) == 0) red[tid >> 6] = v;
  __syncthreads();
  float ssum = 0.f;
#pragma unroll
  for (int i = 0; i < 8; i++) ssum += red[i];

  float a[8];
#pragma unroll
  for (int u = 0; u < 8; u++) a[u] = 0.f;
  const unsigned short* row = Yb + (size_t)tid * WPAD;
  for (int w = 0; w < WPAD; w += 8) {
    ushortx8 f0 = *(const ushortx8*)(row + w);
    float4 s0 = *(const float4*)&soft[w];
    float4 s1 = *(const float4*)&soft[w + 4];
    a[0] += bf2f(f0[0]) * s0.x;
    a[1] += bf2f(f0[1]) * s0.y;
    a[2] += bf2f(f0[2]) * s0.z;
    a[3] += bf2f(f0[3]) * s0.w;
    a[4] += bf2f(f0[4]) * s1.x;
    a[5] += bf2f(f0[5]) * s1.y;
    a[6] += bf2f(f0[6]) * s1.z;
    a[7] += bf2f(f0[7]) * s1.w;
  }
  float asum = ((a[0] + a[1]) + (a[2] + a[3])) + ((a[4] + a[5]) + (a[6] + a[7]));
  float c = asum - cent[(size_t)tid * KGC + k] * ssum;

  __syncthreads();
  float q = c * c;
#pragma unroll
  for (int o = 32; o > 0; o >>= 1) q += __shfl_down(q, o, 64);
  if ((tid & 63) == 0) red[tid >> 6] = q;
  __syncthreads();
  float nsum = 0.f;
#pragma unroll
  for (int i = 0; i < 8; i++) nsum += red[i];
  float norm = sqrtf(nsum);
  float inv = 1.f / fmaxf(norm, 1e-12f);

  float* ob = out + (size_t)b * (NCLU * D_DIM) + (size_t)k * D_DIM;
  ob[tid] = c * inv;
}

extern "C" void kernel_launch(void* const* d_in, const int* in_sizes, int n_in,
                              void* d_out, int out_size, void* d_ws, size_t ws_size,
                              hipStream_t stream) {
  const float* x  = (const float*)d_in[0];
  const float* fw = (const float*)d_in[1];
  const float* fb = (const float*)d_in[2];
  const float* aw = (const float*)d_in[3];
  const float* ab = (const float*)d_in[4];
  const float* ce = (const float*)d_in[5];
  float* out = (float*)d_out;
  char* ws = (char*)d_ws;

  const size_t WC_BYTES = (size_t)MBIG * KDIM * 2;                 //  4,587,520
  const size_t BC_BYTES = 4096;
  const size_t P_BYTES  = (size_t)KSPLIT * 4 * NT * BM * BN * 4;   // 41,943,040
  const size_t XS_BYTES = (size_t)NT * KSG * XTILE * 2;            // 58,720,256
  unsigned short* Wc = (unsigned short*)(ws);
  float*          bc = (float*)(ws + WC_BYTES);
  float*          P  = (float*)(ws + WC_BYTES + BC_BYTES);
  unsigned short* XSp= (unsigned short*)(ws + WC_BYTES + BC_BYTES + P_BYTES);
  // Y (8.65 MB) aliases XS: XS is dead once gemm completes, reduce runs after.
  unsigned short* Yv = XSp;
  // total ws use ~100.4 MiB

  prep2_kernel<<<MBIG + NT * KSG, 256, 0, stream>>>(fw, fb, aw, ab, x, Wc, bc, XSp);
  gemm_fused<<<dim3(NT, 4, KSPLIT), 512, 0, stream>>>(XSp, Wc, P);
  reduce_kernel<<<dim3(NT, 40), 256, 0, stream>>>(P, bc, Yv);
  epi_kernel<<<BATCH * NCLU, 512, 0, stream>>>(Yv, ce, out);
}